// Round 8
// baseline (205.771 us; speedup 1.0000x reference)
//
#include <hip/hip_runtime.h>
#include <math.h>

// Problem constants (fixed by the reference):
#define B_  4
#define C_  256     // in/out channels
#define CI_ 128     // inter channels (attention head dim D)
#define N_  4096    // H*W

typedef short s16x8  __attribute__((ext_vector_type(8)));    // 8 bf16 (4 VGPRs)
typedef float f32x4  __attribute__((ext_vector_type(4)));    // 16x16 accumulator
typedef float f32x16 __attribute__((ext_vector_type(16)));   // 32x32 accumulator

// fp32 -> bf16 (RNE)
__device__ inline ushort f2bf(float f) {
    unsigned int u = __float_as_uint(f);
    u += 0x7FFF + ((u >> 16) & 1);
    return (ushort)(u >> 16);
}
__device__ inline float bf2f(ushort u) {
    return __uint_as_float(((unsigned int)u) << 16);
}

// packed f32x2 -> bf16x2 (RNE)
__device__ inline unsigned pkbf(float a, float b) {
    unsigned r;
    asm("v_cvt_pk_bf16_f32 %0, %1, %2" : "=v"(r) : "v"(a), "v"(b));
    return r;
}
// v_permlane32_swap_b32 x, y
__device__ inline void plswap(unsigned &x, unsigned &y) {
    asm volatile("v_permlane32_swap_b32 %0, %1" : "+v"(x), "+v"(y));
}
// raw v_exp_f32: r = 2^x
__device__ inline float fexp2(float x) {
    float r;
    asm("v_exp_f32 %0, %1" : "=v"(r) : "v"(x));
    return r;
}

// Direct global->LDS DMA, 16B per lane (linear dest, source pre-swizzled).
__device__ inline void gload_lds16(const void* g, void* l) {
    __builtin_amdgcn_global_load_lds(
        (const __attribute__((address_space(1))) unsigned int*)g,
        (__attribute__((address_space(3))) unsigned int*)l, 16, 0, 0);
}

// LDS-only workgroup sync (no vmcnt drain).
__device__ inline void block_sync_lds() {
    asm volatile("s_waitcnt lgkmcnt(0)" ::: "memory");
    __builtin_amdgcn_s_barrier();
    asm volatile("" ::: "memory");
}

#define LOG2E 1.44269504f

// ---------------------------------------------------------------------------
// Prep kernel: weight cast (blocks 0..511) + x transpose+cast (512..1535).
// ---------------------------------------------------------------------------
__global__ __launch_bounds__(256) void prep_kernel(
    const float* __restrict__ Wg, const float* __restrict__ Wt,
    const float* __restrict__ Wp, const float* __restrict__ Wo,
    const float* __restrict__ bg, const float* __restrict__ bt,
    const float* __restrict__ bp,
    ushort* __restrict__ Wcat, ushort* __restrict__ Wobf,
    float* __restrict__ bcat,
    const float* __restrict__ x, ushort* __restrict__ xT)
{
    __shared__ ushort Ls[64][72];
    const int bid = blockIdx.x;
    const int t = threadIdx.x;
    if (bid < 512) {
        int i = bid * 256 + t;
        if (i < 32768)       Wcat[i] = f2bf(Wg[i]);
        else if (i < 65536)  Wcat[i] = f2bf(Wt[i - 32768]);
        else if (i < 98304)  Wcat[i] = f2bf(Wp[i - 65536]);
        else if (i < 131072) Wobf[i - 98304] = f2bf(Wo[i - 98304]);
        if (i < 128)         bcat[i] = bg[i];
        else if (i < 256)    bcat[i] = bt[i - 128];
        else if (i < 384)    bcat[i] = bp[i - 256];
        return;
    }
    int idx2 = bid - 512;
    const int n0 = (idx2 & 63) * 64;
    const int c0 = ((idx2 >> 6) & 3) * 64;
    const int b  = idx2 >> 8;
    const float* xb = x + ((size_t)b * C_ + c0) * N_ + n0;
    #pragma unroll
    for (int r = 0; r < 4; r++) {
        int idx = t + 256 * r;
        int c = idx >> 4, n4 = (idx & 15) * 4;
        float4 v = *(const float4*)&xb[(size_t)c * N_ + n4];
        ushort4 o;
        o.x = f2bf(v.x); o.y = f2bf(v.y); o.z = f2bf(v.z); o.w = f2bf(v.w);
        *(ushort4*)&Ls[c][n4] = o;
    }
    __syncthreads();
    ushort* xTb = xT + ((size_t)b * N_ + n0) * C_ + c0;
    #pragma unroll
    for (int r = 0; r < 2; r++) {
        int idx = t + 256 * r;
        int n = idx >> 3, c8 = (idx & 7) * 8;
        ushort tmp[8];
        #pragma unroll
        for (int u = 0; u < 8; u++) tmp[u] = Ls[c8 + u][n];
        *(uint4*)&xTb[(size_t)n * C_ + c8] = *(uint4*)tmp;
    }
}

// ---------------------------------------------------------------------------
// Projection GEMM: 128x128 tile, BK=64, double-buffered gload_lds staging,
// counted vmcnt(8). Grid (N/128, 3, B). tht pre-scaled by log2e.
// ---------------------------------------------------------------------------
__global__ __launch_bounds__(256, 2) void proj_kernel(
    const ushort* __restrict__ Wcat, const float* __restrict__ bcat,
    const ushort* __restrict__ xT,
    ushort* __restrict__ g, ushort* __restrict__ tht, ushort* __restrict__ pht)
{
    __shared__ __align__(16) char smem[65536];
    const int b = blockIdx.z, mt = blockIdx.y, n0 = blockIdx.x * 128;
    const int t = threadIdx.x, wv = t >> 6, lane = t & 63;
    const int wr = wv >> 1, wc = wv & 1;          // 2x2 wave grid
    const int g4 = lane >> 4, ln = lane & 15;

    const char* Asrc = (const char*)(Wcat + (size_t)mt * 128 * C_);  // row 512B
    const char* Bsrc = (const char*)(xT + ((size_t)b * N_ + n0) * C_);

    const int sr = lane >> 3;            // row within chunk (8 rows x 128B)
    const int sc = (lane & 7) << 4;      // byte col 0..127
    const int ssw = sc ^ (sr << 4);      // pre-swizzled source col

    f32x4 acc[4][4];
    #pragma unroll
    for (int i = 0; i < 4; i++)
        #pragma unroll
        for (int j = 0; j < 4; j++) acc[i][j] = (f32x4){0.f, 0.f, 0.f, 0.f};

    const int rsw = (ln & 7) << 4;       // reader-side XOR swizzle

#define PROJ_STAGE(bufofs, k0) do {                                          \
    _Pragma("unroll")                                                        \
    for (int r_ = 0; r_ < 4; r_++) {                                         \
        int c_   = (wv << 2) + r_;                                           \
        int row_ = (c_ << 3) + sr;                                           \
        gload_lds16(Asrc + (size_t)row_ * 512 + (k0) * 2 + ssw,              \
                    smem + (bufofs) + (c_ << 10));                           \
        gload_lds16(Bsrc + (size_t)row_ * 512 + (k0) * 2 + ssw,              \
                    smem + (bufofs) + 16384 + (c_ << 10));                   \
    }                                                                        \
} while (0)

    PROJ_STAGE(0, 0);
    int buf = 0;
    #pragma unroll
    for (int s = 0; s < 4; s++) {
        if (s < 3) {
            PROJ_STAGE(buf ^ 32768, (s + 1) * 64);
            asm volatile("s_waitcnt vmcnt(8)" ::: "memory");
        } else {
            asm volatile("s_waitcnt vmcnt(0)" ::: "memory");
        }
        __builtin_amdgcn_s_barrier();
        asm volatile("" ::: "memory");

        const char* Ab = smem + buf;
        const char* Bb = smem + buf + 16384;
        #pragma unroll
        for (int kk = 0; kk < 2; kk++) {
            s16x8 aW[4], bX[4];
            #pragma unroll
            for (int m4 = 0; m4 < 4; m4++)
                aW[m4] = *(const s16x8*)(Ab + ((wr * 64 + m4 * 16 + ln) << 7)
                                            + (((kk << 6) + (g4 << 4)) ^ rsw));
            #pragma unroll
            for (int nt = 0; nt < 4; nt++)
                bX[nt] = *(const s16x8*)(Bb + ((wc * 64 + nt * 16 + ln) << 7)
                                            + (((kk << 6) + (g4 << 4)) ^ rsw));
            __builtin_amdgcn_s_setprio(1);
            #pragma unroll
            for (int m4 = 0; m4 < 4; m4++)
                #pragma unroll
                for (int nt = 0; nt < 4; nt++)
                    acc[m4][nt] = __builtin_amdgcn_mfma_f32_16x16x32_bf16(
                        aW[m4], bX[nt], acc[m4][nt], 0, 0, 0);
            __builtin_amdgcn_s_setprio(0);
        }
        block_sync_lds();
        buf ^= 32768;
    }

    if (mt == 0) {
        ushort* ob = g + (size_t)b * CI_ * N_;
        #pragma unroll
        for (int m4 = 0; m4 < 4; m4++) {
            #pragma unroll
            for (int r = 0; r < 4; r++) {
                int m = wr * 64 + m4 * 16 + 4 * g4 + r;
                float bi = bcat[m];
                #pragma unroll
                for (int nt = 0; nt < 4; nt++) {
                    int n = n0 + wc * 64 + nt * 16 + ln;
                    ob[(size_t)m * N_ + n] = f2bf(acc[m4][nt][r] + bi);
                }
            }
        }
    } else {
        ushort* ob = (mt == 1 ? tht : pht) + (size_t)b * N_ * CI_;
        const float* bb = bcat + mt * 128;
        const float scale = (mt == 1) ? LOG2E : 1.0f;
        #pragma unroll
        for (int m4 = 0; m4 < 4; m4++) {
            int mbase = wr * 64 + m4 * 16 + 4 * g4;
            #pragma unroll
            for (int nt = 0; nt < 4; nt++) {
                int n = n0 + wc * 64 + nt * 16 + ln;
                ushort v4[4];
                #pragma unroll
                for (int r = 0; r < 4; r++)
                    v4[r] = f2bf((acc[m4][nt][r] + bb[mbase + r]) * scale);
                *(ushort4*)&ob[(size_t)n * CI_ + mbase] = *(ushort4*)v4;
            }
        }
    }
#undef PROJ_STAGE
}

// ---------------------------------------------------------------------------
// MFMA flash attention, R8: 64 q per wave (256 q/block) — every aK and bV
// LDS read now feeds TWO MFMAs (sub-blocks A and B) -> LDS:MFMA 1:2.
// Spill-proof phase schedule per j-half: QK A+B interleaved (only SA+SB
// live), softmax both (S dies), PV-half immediately (pa-half only).
// Peak liveness ~240 regs, fits (256,2). NC=8 keeps 512 blocks = 2/CU.
// Keeps R7's 16-slot K swizzle + paired-d V layout (conflict-free).
// ---------------------------------------------------------------------------

// Build two PV A-fragments from the 16 in-lane scores of one 32-j S^T tile.
__device__ inline float build_pa(const f32x16& S, s16x8& f0, s16x8& f1) {
    float e[16];
    #pragma unroll
    for (int i = 0; i < 16; i++) e[i] = fexp2(S[i]);
    float t0[8];
    #pragma unroll
    for (int i = 0; i < 8; i++) t0[i] = e[2 * i] + e[2 * i + 1];
    float t1a = (t0[0] + t0[1]) + (t0[2] + t0[3]);
    float t1b = (t0[4] + t0[5]) + (t0[6] + t0[7]);
    float ls = t1a + t1b;
    unsigned w[8];
    #pragma unroll
    for (int i = 0; i < 8; i++) w[i] = pkbf(e[2 * i], e[2 * i + 1]);
    plswap(w[0], w[2]);
    plswap(w[1], w[3]);
    plswap(w[4], w[6]);
    plswap(w[5], w[7]);
    union { unsigned u[4]; s16x8 v; } A, B;
    A.u[0] = w[0]; A.u[1] = w[1]; A.u[2] = w[2]; A.u[3] = w[3];
    B.u[0] = w[4]; B.u[1] = w[5]; B.u[2] = w[6]; B.u[3] = w[7];
    f0 = A.v; f1 = B.v;
    return ls;
}

// Stage one 64-j K/V tile (R7 swizzled layouts).
#define STAGE_KV(bufofs, jsrc) do {                                          \
    _Pragma("unroll")                                                        \
    for (int r_ = 0; r_ < 4; r_++) {                                         \
        int c_   = (wv << 2) + r_;                                           \
        int row_ = (c_ << 2) + srw;                                          \
        int so_  = slt ^ (row_ & 15);                                        \
        gload_lds16(kB + (((jsrc) + row_) << 8) + (so_ << 4),                \
                    smemB + (bufofs) + (c_ << 10));                          \
    }                                                                        \
    _Pragma("unroll")                                                        \
    for (int r_ = 0; r_ < 4; r_++) {                                         \
        int c_   = (wv << 2) + r_;                                           \
        int rr_  = (c_ << 2) + srw;                                          \
        int so_  = slt ^ (rr_ & 15);                                         \
        int d_   = (rr_ << 1) + (so_ >> 3);                                  \
        gload_lds16(vB + (size_t)d_ * (N_ * 2) + ((jsrc) << 1) + ((so_ & 7) << 4), \
                    smemB + (bufofs) + 16384 + (c_ << 10));                  \
    }                                                                        \
} while (0)

template <int NC>
__global__ __launch_bounds__(256, 2) void attn_mfma_kernel(
    const ushort* __restrict__ qn,   // [B][N][CI]  (pre-scaled by log2e)
    const ushort* __restrict__ kn,   // [B][N][CI]
    const ushort* __restrict__ vm,   // [B][CI][N]
    ushort* __restrict__ Opart,     // [NC][B][N][CI] bf16 (unnormalized)
    float* __restrict__ lbuf)        // [NC][B][N] row sums
{
    constexpr int JC = N_ / NC;
    __shared__ __align__(16) char smemB[65536];

    // T1: XCD-bijective chunked swizzle (nb divisible by 8 for NC in {4,8}).
    constexpr int NI = N_ / 256;
    constexpr int nb = NI * NC * B_;
    int flat = (blockIdx.z * NC + blockIdx.y) * NI + blockIdx.x;
    int nf   = (flat & 7) * (nb / 8) + (flat >> 3);
    const int i0    = (nf % NI) * 256;
    const int chunk = (nf / NI) % NC;
    const int b     = nf / (NI * NC);
    const int jbase = chunk * JC;

    const int t    = threadIdx.x;
    const int wv   = t >> 6;
    const int lane = t & 63;
    const int n32  = lane & 31;
    const int h    = lane >> 5;

    // reader swizzles (16-slot)
    const int kswz = (n32 & 15) << 4;          // K rows
    const int vswz = ((n32 >> 1) & 15) << 4;   // V paired rows

    const char* kB = (const char*)(kn + (size_t)b * N_ * CI_);
    const char* vB = (const char*)(vm + (size_t)b * CI_ * N_);

    // Q fragments: wave owns q rows [i0+64*wv, +64); A = +n32, B = +32+n32.
    const ushort* qbw = qn + ((size_t)b * N_ + i0 + 64 * wv) * CI_;
    s16x8 aQA[8], aQB[8];
    #pragma unroll
    for (int kk = 0; kk < 8; kk++) {
        aQA[kk] = *(const s16x8*)(qbw + (size_t)n32 * CI_ + 16 * kk + 8 * h);
        aQB[kk] = *(const s16x8*)(qbw + (size_t)(32 + n32) * CI_ + 16 * kk + 8 * h);
    }

    f32x16 OA[4], OB[4];
    #pragma unroll
    for (int dt = 0; dt < 4; dt++)
        #pragma unroll
        for (int e = 0; e < 16; e++) { OA[dt][e] = 0.f; OB[dt][e] = 0.f; }
    float lsA = 0.f, lsB = 0.f;

    // stager lane constants
    const int srw = lane >> 4;   // row within 4-row chunk
    const int slt = lane & 15;   // 16B slot within 256B row

    STAGE_KV(0, jbase);
    int buf = 0;
    for (int jt = jbase; jt < jbase + JC; jt += 64) {
        if (jt + 64 < jbase + JC) {
            STAGE_KV(buf ^ 32768, jt + 64);
            asm volatile("s_waitcnt vmcnt(8)" ::: "memory");
        } else {
            asm volatile("s_waitcnt vmcnt(0)" ::: "memory");
        }
        __builtin_amdgcn_s_barrier();
        asm volatile("" ::: "memory");

        const char* Kc = smemB + buf;
        const char* Vc = smemB + buf + 16384;

        // Two j-halves of 32; per half: QK(A+B) -> softmax -> PV-half.
        #pragma unroll
        for (int half = 0; half < 2; half++) {
            // ---- QK: each aK read feeds SA and SB (only SA,SB live: 32)
            f32x16 SA, SB;
            #pragma unroll
            for (int e = 0; e < 16; e++) { SA[e] = 0.f; SB[e] = 0.f; }
            __builtin_amdgcn_s_setprio(1);
            #pragma unroll
            for (int kk = 0; kk < 8; kk++) {
                s16x8 aK = *(const s16x8*)(Kc + ((half * 32 + n32) << 8)
                                              + (((kk << 5) + (h << 4)) ^ kswz));
                SA = __builtin_amdgcn_mfma_f32_32x32x16_bf16(aK, aQA[kk], SA, 0, 0, 0);
                SB = __builtin_amdgcn_mfma_f32_32x32x16_bf16(aK, aQB[kk], SB, 0, 0, 0);
            }
            __builtin_amdgcn_s_setprio(0);

            // ---- softmax both sub-blocks (S dies; pa-half = 16 regs)
            s16x8 pA0, pA1, pB0, pB1;
            lsA += build_pa(SA, pA0, pA1);
            lsB += build_pa(SB, pB0, pB1);

            // ---- PV-half: each bV read feeds OA and OB
            __builtin_amdgcn_s_setprio(1);
            #pragma unroll
            for (int dt = 0; dt < 4; dt++) {
                int vrow = (dt << 4) + (n32 >> 1);
                #pragma unroll
                for (int k2 = 0; k2 < 2; k2++) {
                    int kk = half * 2 + k2;
                    s16x8 bV = *(const s16x8*)(Vc + (vrow << 8)
                        + ((((n32 & 1) << 7) + (kk << 5) + (h << 4)) ^ vswz));
                    OA[dt] = __builtin_amdgcn_mfma_f32_32x32x16_bf16(
                        k2 == 0 ? pA0 : pA1, bV, OA[dt], 0, 0, 0);
                    OB[dt] = __builtin_amdgcn_mfma_f32_32x32x16_bf16(
                        k2 == 0 ? pB0 : pB1, bV, OB[dt], 0, 0, 0);
                }
            }
            __builtin_amdgcn_s_setprio(0);
        }

        block_sync_lds();
        buf ^= 32768;
    }

    // ---- epilogue: unnormalized O -> [b][n][d] bf16; l -> lbuf
    ushort* Ob = Opart + (size_t)chunk * (B_ * N_ * CI_)
                       + ((size_t)b * N_ + i0 + 64 * wv) * CI_;
    #pragma unroll
    for (int rg = 0; rg < 16; rg++) {
        int R = (rg & 3) + 8 * (rg >> 2) + 4 * h;
        #pragma unroll
        for (int dt = 0; dt < 4; dt++) {
            Ob[(size_t)R * CI_ + 32 * dt + n32]        = f2bf(OA[dt][rg]);
            Ob[(size_t)(32 + R) * CI_ + 32 * dt + n32] = f2bf(OB[dt][rg]);
        }
    }
    float totA = lsA + __shfl_xor(lsA, 32);
    float totB = lsB + __shfl_xor(lsB, 32);
    if (h == 0) {
        float* lb = lbuf + ((size_t)chunk * B_ + b) * N_ + i0 + 64 * wv;
        lb[n32]      = totA;
        lb[32 + n32] = totB;
    }
}

// ---------------------------------------------------------------------------
// Output GEMM: 128x128 tile, K=128 staged in ONE shot; NC-chunk combine.
// ---------------------------------------------------------------------------
template <int NC>
__global__ __launch_bounds__(256, 2) void outgemm_kernel(
    const ushort* __restrict__ Wobf, const float* __restrict__ bo,
    const ushort* __restrict__ Opart, const float* __restrict__ lbuf,
    const float* __restrict__ x, float* __restrict__ out)
{
    __shared__ __align__(16) char smem[65536];   // W 32KB | Y 32KB
    __shared__ float invL[128];
    const int b = blockIdx.z, m0 = blockIdx.y * 128, n0 = blockIdx.x * 128;
    const int t = threadIdx.x, wv = t >> 6, lane = t & 63;
    const int wr = wv >> 1, wc = wv & 1;
    const int g4 = lane >> 4, ln = lane & 15;
    const size_t cs = (size_t)B_ * N_ * CI_;     // Opart chunk stride

    // ---- issue W staging: 128 rows x 256B = 32 chunks; 8 per wave.
    {
        const char* Wsrc = (const char*)(Wobf + (size_t)m0 * CI_);
        int srl = lane >> 4;
        int scl = (lane & 15) << 4;
        #pragma unroll
        for (int r = 0; r < 8; r++) {
            int c   = (wv << 3) + r;
            int row = (c << 2) + srl;
            gload_lds16(Wsrc + (size_t)row * 256 + (scl ^ ((row & 15) << 4)),
                        smem + (c << 10));
        }
    }

    // ---- 1/l per row
    if (t < 128) {
        float ls = 0.f;
        #pragma unroll
        for (int c = 0; c < NC; c++)
            ls += lbuf[((size_t)c * B_ + b) * N_ + n0 + t];
        invL[t] = 1.0f / ls;
    }
    block_sync_lds();   // invL visible (W DMAs still in flight)

    // ---- stage Y = (sum_c Oc) * invL
    {
        #pragma unroll
        for (int r = 0; r < 8; r++) {
            int c   = t + 256 * r;
            int row = c >> 4;
            int col = (c & 15) << 4;
            size_t obase = ((size_t)b * N_ + n0 + row) * CI_ + (c & 15) * 8;
            float inv = invL[row];
            float osum[8];
            #pragma unroll
            for (int u = 0; u < 8; u++) osum[u] = 0.f;
            #pragma unroll
            for (int cc = 0; cc < NC; cc++) {
                ushort oc[8];
                *(uint4*)oc = *(const uint4*)&Opart[(size_t)cc * cs + obase];
                #pragma unroll
                for (int u = 0; u < 8; u++) osum[u] += bf2f(oc[u]);
            }
            ushort yo[8];
            #pragma unroll
            for (int u = 0; u < 8; u++) yo[u] = f2bf(osum[u] * inv);
            *(uint4*)(smem + 32768 + row * 256 + (col ^ ((row & 15) << 4))) = *(uint4*)yo;
        }
    }
    asm volatile("s_waitcnt vmcnt(0)" ::: "memory");   // W arrived
    block_sync_lds();                                  // Y visible

    // ---- compute: C[m][n] = sum_d W[m][d] Y[n][d], 64 MFMA/wave
    f32x4 acc[4][4];
    #pragma unroll
    for (int i = 0; i < 4; i++)
        #pragma unroll
        for (int j = 0; j < 4; j++) acc[i][j] = (f32x4){0.f, 0.f, 0.f, 0.f};

    const int rsw = ln << 4;
    #pragma unroll
    for (int kk = 0; kk < 4; kk++) {
        s16x8 aW[4], bY[4];
        #pragma unroll
        for (int m4 = 0; m4 < 4; m4++)
            aW[m4] = *(const s16x8*)(smem + ((wr * 64 + m4 * 16 + ln) << 8)
                                          + (((kk << 6) + (g4 << 4)) ^ rsw));
        #pragma unroll
        for (int nt = 0; nt < 4; nt++)
            bY[nt] = *(const s16x8*)(smem + 32768 + ((wc * 64 + nt * 16 + ln) << 8)
                                          + (((kk << 6) + (g4 << 4)) ^ rsw));
        __builtin_amdgcn_s_setprio(1);
        #pragma unroll
        for (int m4 = 0; m4 < 4; m4++)
            #pragma unroll
            for (int nt = 0; nt < 4; nt++)
                acc[m4][nt] = __builtin_amdgcn_mfma_f32_16x16x32_bf16(
                    aW[m4], bY[nt], acc[m4][nt], 0, 0, 0);
        __builtin_amdgcn_s_setprio(0);
    }

    // ---- epilogue: out = acc + bo + x
    float* outb = out + (size_t)b * C_ * N_;
    const float* xb = x + (size_t)b * C_ * N_;
    #pragma unroll
    for (int m4 = 0; m4 < 4; m4++) {
        #pragma unroll
        for (int r = 0; r < 4; r++) {
            int m = m0 + wr * 64 + m4 * 16 + 4 * g4 + r;
            float bi = bo[m];
            #pragma unroll
            for (int nt = 0; nt < 4; nt++) {
                size_t idx = (size_t)m * N_ + n0 + wc * 64 + nt * 16 + ln;
                outb[idx] = acc[m4][nt][r] + bi + xb[idx];
            }
        }
    }
}

// ---------------------------------------------------------------------------
extern "C" void kernel_launch(void* const* d_in, const int* in_sizes, int n_in,
                              void* d_out, int out_size, void* d_ws, size_t ws_size,
                              hipStream_t stream) {
    const float* x  = (const float*)d_in[0];
    const float* Wg = (const float*)d_in[1];
    const float* bg = (const float*)d_in[2];
    const float* Wt = (const float*)d_in[3];
    const float* bt = (const float*)d_in[4];
    const float* Wp = (const float*)d_in[5];
    const float* bp = (const float*)d_in[6];
    const float* Wo = (const float*)d_in[7];
    const float* bo = (const float*)d_in[8];
    float* out = (float*)d_out;

    // NC=8 needs 46,925,312 B (verified available in R2); else NC=4.
    const bool big = ws_size >= 46925312ull;
    const int NC = big ? 8 : 4;

    char* w = (char*)d_ws;
    size_t opart_sz = (size_t)NC * B_ * N_ * CI_ * sizeof(ushort);
    ushort* xT    = (ushort*)w;                        // [B][N][C] bf16 (dead after proj)
    ushort* Opart = (ushort*)w;                        // [NC][B][N][CI] bf16 (aliases xT)
    ushort* g     = (ushort*)(w + opart_sz);           // [B][CI][N] bf16, 4MB
    ushort* tht   = (ushort*)(w + opart_sz + 4194304); // [B][N][CI] bf16, 4MB
    ushort* pht   = (ushort*)(w + opart_sz + 8388608); // [B][N][CI] bf16, 4MB
    ushort* Wcat  = (ushort*)(w + opart_sz + 12582912);          // [384][256] bf16
    ushort* Wobf  = (ushort*)(w + opart_sz + 12582912 + 196608); // [256][128] bf16
    float*  bcat  = (float*) (w + opart_sz + 12582912 + 262144); // [384]
    float*  lbuf  = (float*) (w + opart_sz + 12582912 + 263680); // [NC][B][N] fp32

    dim3 blk(256);
    prep_kernel<<<1536, blk, 0, stream>>>(Wg, Wt, Wp, Wo, bg, bt, bp,
                                          Wcat, Wobf, bcat, x, xT);
    proj_kernel<<<dim3(N_ / 128, 3, B_), blk, 0, stream>>>(Wcat, bcat, xT, g, tht, pht);
    if (big) {
        attn_mfma_kernel<8><<<dim3(N_ / 256, 8, B_), blk, 0, stream>>>(tht, pht, g, Opart, lbuf);
        outgemm_kernel<8><<<dim3(N_ / 128, C_ / 128, B_), blk, 0, stream>>>(Wobf, bo, Opart, lbuf, x, out);
    } else {
        attn_mfma_kernel<4><<<dim3(N_ / 256, 4, B_), blk, 0, stream>>>(tht, pht, g, Opart, lbuf);
        outgemm_kernel<4><<<dim3(N_ / 128, C_ / 128, B_), blk, 0, stream>>>(Wobf, bo, Opart, lbuf, x, out);
    }
}

// Round 9
// 141.143 us; speedup vs baseline: 1.4579x; 1.4579x over previous
//
#include <hip/hip_runtime.h>
#include <math.h>

// Problem constants (fixed by the reference):
#define B_  4
#define C_  256     // in/out channels
#define CI_ 128     // inter channels (attention head dim D)
#define N_  4096    // H*W

typedef short s16x8  __attribute__((ext_vector_type(8)));    // 8 bf16 (4 VGPRs)
typedef float f32x4  __attribute__((ext_vector_type(4)));    // 16x16 accumulator
typedef float f32x16 __attribute__((ext_vector_type(16)));   // 32x32 accumulator

// fp32 -> bf16 (RNE)
__device__ inline ushort f2bf(float f) {
    unsigned int u = __float_as_uint(f);
    u += 0x7FFF + ((u >> 16) & 1);
    return (ushort)(u >> 16);
}
__device__ inline float bf2f(ushort u) {
    return __uint_as_float(((unsigned int)u) << 16);
}

// packed f32x2 -> bf16x2 (RNE)
__device__ inline unsigned pkbf(float a, float b) {
    unsigned r;
    asm("v_cvt_pk_bf16_f32 %0, %1, %2" : "=v"(r) : "v"(a), "v"(b));
    return r;
}
// v_permlane32_swap_b32 x, y
__device__ inline void plswap(unsigned &x, unsigned &y) {
    asm volatile("v_permlane32_swap_b32 %0, %1" : "+v"(x), "+v"(y));
}
// raw v_exp_f32: r = 2^x (VALU deps are HW-interlocked; no libcall)
__device__ inline float fexp2(float x) {
    float r;
    asm("v_exp_f32 %0, %1" : "=v"(r) : "v"(x));
    return r;
}

// Direct global->LDS DMA, 16B per lane (linear dest, source pre-swizzled).
__device__ inline void gload_lds16(const void* g, void* l) {
    __builtin_amdgcn_global_load_lds(
        (const __attribute__((address_space(1))) unsigned int*)g,
        (__attribute__((address_space(3))) unsigned int*)l, 16, 0, 0);
}

// LDS-only workgroup sync (no vmcnt drain).
__device__ inline void block_sync_lds() {
    asm volatile("s_waitcnt lgkmcnt(0)" ::: "memory");
    __builtin_amdgcn_s_barrier();
    asm volatile("" ::: "memory");
}

#define LOG2E 1.44269504f

// ---------------------------------------------------------------------------
// Prep kernel: fuses weight cast (blocks 0..511) and x transpose+cast
// (blocks 512..1535).
// ---------------------------------------------------------------------------
__global__ __launch_bounds__(256) void prep_kernel(
    const float* __restrict__ Wg, const float* __restrict__ Wt,
    const float* __restrict__ Wp, const float* __restrict__ Wo,
    const float* __restrict__ bg, const float* __restrict__ bt,
    const float* __restrict__ bp,
    ushort* __restrict__ Wcat, ushort* __restrict__ Wobf,
    float* __restrict__ bcat,
    const float* __restrict__ x, ushort* __restrict__ xT)
{
    __shared__ ushort Ls[64][72];
    const int bid = blockIdx.x;
    const int t = threadIdx.x;
    if (bid < 512) {
        int i = bid * 256 + t;
        if (i < 32768)       Wcat[i] = f2bf(Wg[i]);
        else if (i < 65536)  Wcat[i] = f2bf(Wt[i - 32768]);
        else if (i < 98304)  Wcat[i] = f2bf(Wp[i - 65536]);
        else if (i < 131072) Wobf[i - 98304] = f2bf(Wo[i - 98304]);
        if (i < 128)         bcat[i] = bg[i];
        else if (i < 256)    bcat[i] = bt[i - 128];
        else if (i < 384)    bcat[i] = bp[i - 256];
        return;
    }
    // xt part: decode (64, 4, 4)
    int idx2 = bid - 512;
    const int n0 = (idx2 & 63) * 64;
    const int c0 = ((idx2 >> 6) & 3) * 64;
    const int b  = idx2 >> 8;
    const float* xb = x + ((size_t)b * C_ + c0) * N_ + n0;
    #pragma unroll
    for (int r = 0; r < 4; r++) {
        int idx = t + 256 * r;
        int c = idx >> 4, n4 = (idx & 15) * 4;
        float4 v = *(const float4*)&xb[(size_t)c * N_ + n4];
        ushort4 o;
        o.x = f2bf(v.x); o.y = f2bf(v.y); o.z = f2bf(v.z); o.w = f2bf(v.w);
        *(ushort4*)&Ls[c][n4] = o;
    }
    __syncthreads();
    ushort* xTb = xT + ((size_t)b * N_ + n0) * C_ + c0;
    #pragma unroll
    for (int r = 0; r < 2; r++) {
        int idx = t + 256 * r;
        int n = idx >> 3, c8 = (idx & 7) * 8;
        ushort tmp[8];
        #pragma unroll
        for (int u = 0; u < 8; u++) tmp[u] = Ls[c8 + u][n];
        *(uint4*)&xTb[(size_t)n * C_ + c8] = *(uint4*)tmp;
    }
}

// ---------------------------------------------------------------------------
// Projection GEMM: 128x128 tile, BK=64, double-buffered gload_lds staging,
// counted vmcnt(8). Grid (N/128, 3, B): mt=0 -> g; mt=1 -> tht (pre-scaled
// by log2e for the exp2 softmax); mt=2 -> pht.
// ---------------------------------------------------------------------------
__global__ __launch_bounds__(256, 2) void proj_kernel(
    const ushort* __restrict__ Wcat, const float* __restrict__ bcat,
    const ushort* __restrict__ xT,
    ushort* __restrict__ g, ushort* __restrict__ tht, ushort* __restrict__ pht)
{
    __shared__ __align__(16) char smem[65536];
    const int b = blockIdx.z, mt = blockIdx.y, n0 = blockIdx.x * 128;
    const int t = threadIdx.x, wv = t >> 6, lane = t & 63;
    const int wr = wv >> 1, wc = wv & 1;          // 2x2 wave grid
    const int g4 = lane >> 4, ln = lane & 15;

    const char* Asrc = (const char*)(Wcat + (size_t)mt * 128 * C_);  // row 512B
    const char* Bsrc = (const char*)(xT + ((size_t)b * N_ + n0) * C_);

    const int sr = lane >> 3;            // row within chunk (8 rows x 128B)
    const int sc = (lane & 7) << 4;      // byte col 0..127
    const int ssw = sc ^ (sr << 4);      // pre-swizzled source col

    f32x4 acc[4][4];
    #pragma unroll
    for (int i = 0; i < 4; i++)
        #pragma unroll
        for (int j = 0; j < 4; j++) acc[i][j] = (f32x4){0.f, 0.f, 0.f, 0.f};

    const int rsw = (ln & 7) << 4;       // reader-side XOR swizzle

#define PROJ_STAGE(bufofs, k0) do {                                          \
    _Pragma("unroll")                                                        \
    for (int r_ = 0; r_ < 4; r_++) {                                         \
        int c_   = (wv << 2) + r_;                                           \
        int row_ = (c_ << 3) + sr;                                           \
        gload_lds16(Asrc + (size_t)row_ * 512 + (k0) * 2 + ssw,              \
                    smem + (bufofs) + (c_ << 10));                           \
        gload_lds16(Bsrc + (size_t)row_ * 512 + (k0) * 2 + ssw,              \
                    smem + (bufofs) + 16384 + (c_ << 10));                   \
    }                                                                        \
} while (0)

    PROJ_STAGE(0, 0);
    int buf = 0;
    #pragma unroll
    for (int s = 0; s < 4; s++) {
        if (s < 3) {
            PROJ_STAGE(buf ^ 32768, (s + 1) * 64);
            asm volatile("s_waitcnt vmcnt(8)" ::: "memory");
        } else {
            asm volatile("s_waitcnt vmcnt(0)" ::: "memory");
        }
        __builtin_amdgcn_s_barrier();
        asm volatile("" ::: "memory");

        const char* Ab = smem + buf;
        const char* Bb = smem + buf + 16384;
        #pragma unroll
        for (int kk = 0; kk < 2; kk++) {
            s16x8 aW[4], bX[4];
            #pragma unroll
            for (int m4 = 0; m4 < 4; m4++)
                aW[m4] = *(const s16x8*)(Ab + ((wr * 64 + m4 * 16 + ln) << 7)
                                            + (((kk << 6) + (g4 << 4)) ^ rsw));
            #pragma unroll
            for (int nt = 0; nt < 4; nt++)
                bX[nt] = *(const s16x8*)(Bb + ((wc * 64 + nt * 16 + ln) << 7)
                                            + (((kk << 6) + (g4 << 4)) ^ rsw));
            __builtin_amdgcn_s_setprio(1);
            #pragma unroll
            for (int m4 = 0; m4 < 4; m4++)
                #pragma unroll
                for (int nt = 0; nt < 4; nt++)
                    acc[m4][nt] = __builtin_amdgcn_mfma_f32_16x16x32_bf16(
                        aW[m4], bX[nt], acc[m4][nt], 0, 0, 0);
            __builtin_amdgcn_s_setprio(0);
        }
        block_sync_lds();
        buf ^= 32768;
    }

    if (mt == 0) {
        // g: [CI][N], m-major
        ushort* ob = g + (size_t)b * CI_ * N_;
        #pragma unroll
        for (int m4 = 0; m4 < 4; m4++) {
            #pragma unroll
            for (int r = 0; r < 4; r++) {
                int m = wr * 64 + m4 * 16 + 4 * g4 + r;
                float bi = bcat[m];
                #pragma unroll
                for (int nt = 0; nt < 4; nt++) {
                    int n = n0 + wc * 64 + nt * 16 + ln;
                    ob[(size_t)m * N_ + n] = f2bf(acc[m4][nt][r] + bi);
                }
            }
        }
    } else {
        // tht/pht: [N][CI]; tht pre-scaled by log2e.
        ushort* ob = (mt == 1 ? tht : pht) + (size_t)b * N_ * CI_;
        const float* bb = bcat + mt * 128;
        const float scale = (mt == 1) ? LOG2E : 1.0f;
        #pragma unroll
        for (int m4 = 0; m4 < 4; m4++) {
            int mbase = wr * 64 + m4 * 16 + 4 * g4;
            #pragma unroll
            for (int nt = 0; nt < 4; nt++) {
                int n = n0 + wc * 64 + nt * 16 + ln;
                ushort v4[4];
                #pragma unroll
                for (int r = 0; r < 4; r++)
                    v4[r] = f2bf((acc[m4][nt][r] + bb[mbase + r]) * scale);
                *(ushort4*)&ob[(size_t)n * CI_ + mbase] = *(ushort4*)v4;
            }
        }
    }
#undef PROJ_STAGE
}

// ---------------------------------------------------------------------------
// MFMA flash attention (R7 structure — best verified):
//  - serial S0 -> softmax0 -> S1 -> softmax1 (softmax hides under the other
//    chain's MFMAs)
//  - raw v_exp_f32 on pre-scaled scores
//  - 16-slot XOR swizzle for K (256B rows) and paired-d V layout -> 0 bank
//    conflicts on both ds_read_b128 streams
//  - double-buffered LDS (2x32KB) with counted vmcnt(8)
// ---------------------------------------------------------------------------

// Build two PV A-fragments from the 16 in-lane scores of one 32-j S^T tile.
// S is pre-scaled by log2e; P = exp2(S). Returns fp32 tree row-sum.
__device__ inline float build_pa(const f32x16& S, s16x8& f0, s16x8& f1) {
    float e[16];
    #pragma unroll
    for (int i = 0; i < 16; i++) e[i] = fexp2(S[i]);
    float t0[8];
    #pragma unroll
    for (int i = 0; i < 8; i++) t0[i] = e[2 * i] + e[2 * i + 1];
    float t1a = (t0[0] + t0[1]) + (t0[2] + t0[3]);
    float t1b = (t0[4] + t0[5]) + (t0[6] + t0[7]);
    float ls = t1a + t1b;
    unsigned w[8];
    #pragma unroll
    for (int i = 0; i < 8; i++) w[i] = pkbf(e[2 * i], e[2 * i + 1]);
    plswap(w[0], w[2]);
    plswap(w[1], w[3]);
    plswap(w[4], w[6]);
    plswap(w[5], w[7]);
    union { unsigned u[4]; s16x8 v; } A, B;
    A.u[0] = w[0]; A.u[1] = w[1]; A.u[2] = w[2]; A.u[3] = w[3];
    B.u[0] = w[4]; B.u[1] = w[5]; B.u[2] = w[6]; B.u[3] = w[7];
    f0 = A.v; f1 = B.v;
    return ls;
}

// Stage one 64-j K/V tile. K: 64 rows x 256B, 16-slot XOR swizzle.
// V: 64 paired rows x 256B (row r = d=2r | d=2r+1), 16-slot XOR swizzle.
#define STAGE_KV(bufofs, jsrc) do {                                          \
    _Pragma("unroll")                                                        \
    for (int r_ = 0; r_ < 4; r_++) {                                         \
        int c_   = (wv << 2) + r_;                                           \
        int row_ = (c_ << 2) + srw;                                          \
        int so_  = slt ^ (row_ & 15);                                        \
        gload_lds16(kB + (((jsrc) + row_) << 8) + (so_ << 4),                \
                    smemB + (bufofs) + (c_ << 10));                          \
    }                                                                        \
    _Pragma("unroll")                                                        \
    for (int r_ = 0; r_ < 4; r_++) {                                         \
        int c_   = (wv << 2) + r_;                                           \
        int rr_  = (c_ << 2) + srw;                                          \
        int so_  = slt ^ (rr_ & 15);                                         \
        int d_   = (rr_ << 1) + (so_ >> 3);                                  \
        gload_lds16(vB + (size_t)d_ * (N_ * 2) + ((jsrc) << 1) + ((so_ & 7) << 4), \
                    smemB + (bufofs) + 16384 + (c_ << 10));                  \
    }                                                                        \
} while (0)

#define NC_ 4
#define JC_ (N_ / NC_)

__global__ __launch_bounds__(256, 2) void attn_mfma_kernel(
    const ushort* __restrict__ qn,   // [B][N][CI]  (pre-scaled by log2e)
    const ushort* __restrict__ kn,   // [B][N][CI]
    const ushort* __restrict__ vm,   // [B][CI][N]
    ushort* __restrict__ Opart,      // [NC][B][N][CI] bf16 (unnormalized)
    float* __restrict__ lbuf)        // [NC][B][N] row sums
{
    __shared__ __align__(16) char smemB[65536];

    constexpr int NI = N_ / 128;
    constexpr int nb = NI * NC_ * B_;
    int flat = (blockIdx.z * NC_ + blockIdx.y) * NI + blockIdx.x;
    int nf   = (flat & 7) * (nb / 8) + (flat >> 3);
    const int i0    = (nf % NI) * 128;
    const int chunk = (nf / NI) % NC_;
    const int b     = nf / (NI * NC_);
    const int jbase = chunk * JC_;

    const int t    = threadIdx.x;
    const int wv   = t >> 6;
    const int lane = t & 63;
    const int n32  = lane & 31;
    const int h    = lane >> 5;

    // reader swizzles (16-slot)
    const int kswz = (n32 & 15) << 4;          // K rows: row&15 == n32&15
    const int vswz = ((n32 >> 1) & 15) << 4;   // V rows: row&15 == (n32>>1)&15

    const char* kB = (const char*)(kn + (size_t)b * N_ * CI_);
    const char* vB = (const char*)(vm + (size_t)b * CI_ * N_);

    const ushort* qb = qn + ((size_t)b * N_ + i0) * CI_;
    s16x8 aQ[8];
    #pragma unroll
    for (int kk = 0; kk < 8; kk++)
        aQ[kk] = *(const s16x8*)(qb + (size_t)(32 * wv + n32) * CI_ + 16 * kk + 8 * h);

    f32x16 Oacc[4];
    #pragma unroll
    for (int dt = 0; dt < 4; dt++)
        #pragma unroll
        for (int e = 0; e < 16; e++) Oacc[dt][e] = 0.f;
    float lsum = 0.f;

    // stager lane constants
    const int srw = lane >> 4;   // row within 4-row chunk
    const int slt = lane & 15;   // 16B slot within 256B row

    STAGE_KV(0, jbase);
    int buf = 0;
    for (int jt = jbase; jt < jbase + JC_; jt += 64) {
        if (jt + 64 < jbase + JC_) {
            STAGE_KV(buf ^ 32768, jt + 64);
            asm volatile("s_waitcnt vmcnt(8)" ::: "memory");
        } else {
            asm volatile("s_waitcnt vmcnt(0)" ::: "memory");
        }
        __builtin_amdgcn_s_barrier();
        asm volatile("" ::: "memory");

        const char* Kc = smemB + buf;
        const char* Vc = smemB + buf + 16384;

        // ---- S0^T = K[0:32] Q^T, softmax0 (overlaps with S1's chain)
        s16x8 pa[4];
        {
            f32x16 S0;
            #pragma unroll
            for (int e = 0; e < 16; e++) S0[e] = 0.f;
            __builtin_amdgcn_s_setprio(1);
            #pragma unroll
            for (int kk = 0; kk < 8; kk++) {
                s16x8 aK = *(const s16x8*)(Kc + (n32 << 8)
                                              + (((kk << 5) + (h << 4)) ^ kswz));
                S0 = __builtin_amdgcn_mfma_f32_32x32x16_bf16(aK, aQ[kk], S0, 0, 0, 0);
            }
            __builtin_amdgcn_s_setprio(0);
            lsum += build_pa(S0, pa[0], pa[1]);   // j 0..31 -> k-slots 0,1
        }
        // ---- S1^T = K[32:64] Q^T, softmax1
        {
            f32x16 S1;
            #pragma unroll
            for (int e = 0; e < 16; e++) S1[e] = 0.f;
            __builtin_amdgcn_s_setprio(1);
            #pragma unroll
            for (int kk = 0; kk < 8; kk++) {
                s16x8 aK = *(const s16x8*)(Kc + ((32 + n32) << 8)
                                              + (((kk << 5) + (h << 4)) ^ kswz));
                S1 = __builtin_amdgcn_mfma_f32_32x32x16_bf16(aK, aQ[kk], S1, 0, 0, 0);
            }
            __builtin_amdgcn_s_setprio(0);
            lsum += build_pa(S1, pa[2], pa[3]);   // j 32..63 -> k-slots 2,3
        }

        // ---- PV: O[32q x 128d] += P[32q x 64j] V[64j x 128d]
        // V row = 16*dt + (n32>>1), half = n32&1 (paired-d layout)
        __builtin_amdgcn_s_setprio(1);
        #pragma unroll
        for (int dt = 0; dt < 4; dt++) {
            int vrow = (dt << 4) + (n32 >> 1);
            #pragma unroll
            for (int kk = 0; kk < 4; kk++) {
                s16x8 bV = *(const s16x8*)(Vc + (vrow << 8)
                    + ((((n32 & 1) << 7) + (kk << 5) + (h << 4)) ^ vswz));
                Oacc[dt] = __builtin_amdgcn_mfma_f32_32x32x16_bf16(pa[kk], bV, Oacc[dt], 0, 0, 0);
            }
        }
        __builtin_amdgcn_s_setprio(0);

        block_sync_lds();
        buf ^= 32768;
    }

    ushort* Ob = Opart + (size_t)chunk * (B_ * N_ * CI_) + ((size_t)b * N_ + i0) * CI_;
    #pragma unroll
    for (int rg = 0; rg < 16; rg++) {
        int R = (rg & 3) + 8 * (rg >> 2) + 4 * h;
        int q = 32 * wv + R;
        #pragma unroll
        for (int dt = 0; dt < 4; dt++)
            Ob[(size_t)q * CI_ + 32 * dt + n32] = f2bf(Oacc[dt][rg]);
    }
    float ot  = __shfl_xor(lsum, 32);
    float tot = lsum + ot;
    if (h == 0)
        lbuf[((size_t)chunk * B_ + b) * N_ + i0 + 32 * wv + n32] = tot;
}

// ---------------------------------------------------------------------------
// Output GEMM: 128x128 tile, K=128 staged in ONE shot.
// ---------------------------------------------------------------------------
__global__ __launch_bounds__(256, 2) void outgemm_kernel(
    const ushort* __restrict__ Wobf, const float* __restrict__ bo,
    const ushort* __restrict__ Opart, const float* __restrict__ lbuf,
    const float* __restrict__ x, float* __restrict__ out)
{
    __shared__ __align__(16) char smem[65536];   // W 32KB | Y 32KB
    __shared__ float invL[128];
    const int b = blockIdx.z, m0 = blockIdx.y * 128, n0 = blockIdx.x * 128;
    const int t = threadIdx.x, wv = t >> 6, lane = t & 63;
    const int wr = wv >> 1, wc = wv & 1;
    const int g4 = lane >> 4, ln = lane & 15;
    const size_t cs = (size_t)B_ * N_ * CI_;     // Opart chunk stride

    // ---- issue W staging: 128 rows x 256B = 32 chunks; 8 per wave.
    {
        const char* Wsrc = (const char*)(Wobf + (size_t)m0 * CI_);
        int srl = lane >> 4;                 // row within chunk (0..3)
        int scl = (lane & 15) << 4;          // byte col 0..240
        #pragma unroll
        for (int r = 0; r < 8; r++) {
            int c   = (wv << 3) + r;
            int row = (c << 2) + srl;
            gload_lds16(Wsrc + (size_t)row * 256 + (scl ^ ((row & 15) << 4)),
                        smem + (c << 10));
        }
    }

    // ---- 1/l per row
    if (t < 128) {
        float ls = 0.f;
        #pragma unroll
        for (int c = 0; c < NC_; c++)
            ls += lbuf[((size_t)c * B_ + b) * N_ + n0 + t];
        invL[t] = 1.0f / ls;
    }
    block_sync_lds();   // invL visible (W DMAs still in flight)

    // ---- stage Y = (sum_c Oc) * invL
    {
        #pragma unroll
        for (int r = 0; r < 8; r++) {
            int c   = t + 256 * r;
            int row = c >> 4;
            int col = (c & 15) << 4;
            size_t obase = ((size_t)b * N_ + n0 + row) * CI_ + (c & 15) * 8;
            float inv = invL[row];
            float osum[8];
            #pragma unroll
            for (int u = 0; u < 8; u++) osum[u] = 0.f;
            #pragma unroll
            for (int cc = 0; cc < NC_; cc++) {
                ushort oc[8];
                *(uint4*)oc = *(const uint4*)&Opart[(size_t)cc * cs + obase];
                #pragma unroll
                for (int u = 0; u < 8; u++) osum[u] += bf2f(oc[u]);
            }
            ushort yo[8];
            #pragma unroll
            for (int u = 0; u < 8; u++) yo[u] = f2bf(osum[u] * inv);
            *(uint4*)(smem + 32768 + row * 256 + (col ^ ((row & 15) << 4))) = *(uint4*)yo;
        }
    }
    asm volatile("s_waitcnt vmcnt(0)" ::: "memory");   // W arrived
    block_sync_lds();                                  // Y visible

    // ---- compute: C[m][n] = sum_d W[m][d] Y[n][d], 64 MFMA/wave
    f32x4 acc[4][4];
    #pragma unroll
    for (int i = 0; i < 4; i++)
        #pragma unroll
        for (int j = 0; j < 4; j++) acc[i][j] = (f32x4){0.f, 0.f, 0.f, 0.f};

    const int rsw = ln << 4;
    #pragma unroll
    for (int kk = 0; kk < 4; kk++) {
        s16x8 aW[4], bY[4];
        #pragma unroll
        for (int m4 = 0; m4 < 4; m4++)
            aW[m4] = *(const s16x8*)(smem + ((wr * 64 + m4 * 16 + ln) << 8)
                                          + (((kk << 6) + (g4 << 4)) ^ rsw));
        #pragma unroll
        for (int nt = 0; nt < 4; nt++)
            bY[nt] = *(const s16x8*)(smem + 32768 + ((wc * 64 + nt * 16 + ln) << 8)
                                          + (((kk << 6) + (g4 << 4)) ^ rsw));
        __builtin_amdgcn_s_setprio(1);
        #pragma unroll
        for (int m4 = 0; m4 < 4; m4++)
            #pragma unroll
            for (int nt = 0; nt < 4; nt++)
                acc[m4][nt] = __builtin_amdgcn_mfma_f32_16x16x32_bf16(
                    aW[m4], bY[nt], acc[m4][nt], 0, 0, 0);
        __builtin_amdgcn_s_setprio(0);
    }

    // ---- epilogue: out = acc + bo + x
    float* outb = out + (size_t)b * C_ * N_;
    const float* xb = x + (size_t)b * C_ * N_;
    #pragma unroll
    for (int m4 = 0; m4 < 4; m4++) {
        #pragma unroll
        for (int r = 0; r < 4; r++) {
            int m = m0 + wr * 64 + m4 * 16 + 4 * g4 + r;
            float bi = bo[m];
            #pragma unroll
            for (int nt = 0; nt < 4; nt++) {
                size_t idx = (size_t)m * N_ + n0 + wc * 64 + nt * 16 + ln;
                outb[idx] = acc[m4][nt][r] + bi + xb[idx];
            }
        }
    }
}

// ---------------------------------------------------------------------------
extern "C" void kernel_launch(void* const* d_in, const int* in_sizes, int n_in,
                              void* d_out, int out_size, void* d_ws, size_t ws_size,
                              hipStream_t stream) {
    const float* x  = (const float*)d_in[0];
    const float* Wg = (const float*)d_in[1];
    const float* bg = (const float*)d_in[2];
    const float* Wt = (const float*)d_in[3];
    const float* bt = (const float*)d_in[4];
    const float* Wp = (const float*)d_in[5];
    const float* bp = (const float*)d_in[6];
    const float* Wo = (const float*)d_in[7];
    const float* bo = (const float*)d_in[8];
    float* out = (float*)d_out;

    // ws layout (bytes), NC=4. xT (8 MB) dead after proj; Opart aliases it.
    char* w = (char*)d_ws;
    ushort* xT    = (ushort*)w;                   // [B][N][C]  bf16, 8 MB
    ushort* Opart = (ushort*)w;                   // [4][B][N][CI] bf16, 16 MB
    ushort* g     = (ushort*)(w + 16777216);      // [B][CI][N] bf16, 4 MB
    ushort* tht   = (ushort*)(w + 20971520);      // [B][N][CI] bf16, 4 MB
    ushort* pht   = (ushort*)(w + 25165824);      // [B][N][CI] bf16, 4 MB
    ushort* Wcat  = (ushort*)(w + 29360128);      // [384][256] bf16
    ushort* Wobf  = (ushort*)(w + 29556736);      // [256][128] bf16
    float*  bcat  = (float*) (w + 29622272);      // [384]
    float*  lbuf  = (float*) (w + 29623808);      // [4][B][N] fp32, 256 KB

    dim3 blk(256);
    prep_kernel<<<1536, blk, 0, stream>>>(Wg, Wt, Wp, Wo, bg, bt, bp,
                                          Wcat, Wobf, bcat, x, xT);
    proj_kernel<<<dim3(N_ / 128, 3, B_), blk, 0, stream>>>(Wcat, bcat, xT, g, tht, pht);
    attn_mfma_kernel<<<dim3(N_ / 128, NC_, B_), blk, 0, stream>>>(tht, pht, g, Opart, lbuf);
    outgemm_kernel<<<dim3(N_ / 128, C_ / 128, B_), blk, 0, stream>>>(Wobf, bo, Opart, lbuf, x, out);
}